// Round 1
// baseline (403.621 us; speedup 1.0000x reference)
//
#include <hip/hip_runtime.h>
#include <math.h>

#define Bn   128
#define Sn   512
#define HIDn 768
#define OUTn 200
#define MSEG 16
#define NPAD 224   // OUT padded to 14 MFMA n-tiles of 16
#define NT   14
#define NTW  7     // n-tiles per wave (N split across the 2 waves of a row-half pair)
#define KIT  (HIDn / 32)   // 24 k-iterations

typedef __attribute__((ext_vector_type(8))) short short8;
typedef __attribute__((ext_vector_type(4))) float f32x4;

// fp32 -> bf16 round-to-nearest-even (finite inputs)
static __device__ inline unsigned short f2bf(float f) {
  union { float f; unsigned u; } v; v.f = f;
  unsigned r = v.u + 0x7FFFu + ((v.u >> 16) & 1u);
  return (unsigned short)(r >> 16);
}

// saturating fast tanh: e = exp(-2|x|) in (0,1], never overflows
static __device__ inline float fast_tanh(float x) {
  float t = fabsf(x);
  float e = __expf(-2.f * t);
  float r = (1.f - e) * __builtin_amdgcn_rcpf(1.f + e);
  return copysignf(r, x);
}

// one-time: WhF = bf16(Wh^T) in MFMA B-fragment order:
// elem (n,k) -> ((k>>5)*NT + (n>>4))*512 + ((k>>3)&3)*128 + (n&15)*8 + (k&7)
// per (k-tile, n-tile) a wave's fragment is one contiguous 1 KB chunk at
// base + lane*16.  Cols 200..223 zero-padded.  vP = v zero-padded to NPAD.
__global__ __launch_bounds__(256) void setup_kernel(
    const float* __restrict__ Wh, const float* __restrict__ v,
    unsigned short* __restrict__ WhF, float* __restrict__ vP) {
  int idx = blockIdx.x * 256 + threadIdx.x;   // grid 672 -> 172032 = NPAD*HIDn
  if (blockIdx.x == 0 && threadIdx.x < NPAD)
    vP[threadIdx.x] = (threadIdx.x < OUTn) ? v[threadIdx.x] : 0.f;
  if (idx < NPAD * HIDn) {
    int n = idx / HIDn;
    int k = idx - n * HIDn;
    float val = (n < OUTn) ? Wh[(size_t)k * OUTn + n] : 0.f;
    size_t d = ((size_t)(k >> 5) * NT + (n >> 4)) * 512
             + ((k >> 3) & 3) * 128 + (n & 15) * 8 + (k & 7);
    WhF[d] = f2bf(val);
  }
}

// biasP[b][n] = b[n] + u[b]@Wu[:,n] + p[b]@Wp[:,n], zero-padded to NPAD
__global__ __launch_bounds__(256) void bias_kernel(
    const float* __restrict__ u, const float* __restrict__ p,
    const float* __restrict__ Wu, const float* __restrict__ Wp,
    const float* __restrict__ bvec, float* __restrict__ biasP) {
  int b = blockIdx.x;
  __shared__ float ul[OUTn], pl[OUTn];
  int tid = threadIdx.x;
  if (tid < OUTn) { ul[tid] = u[b * OUTn + tid]; pl[tid] = p[b * OUTn + tid]; }
  __syncthreads();
  if (tid < NPAD) {
    float s0 = 0.f, s1 = 0.f;
    if (tid < OUTn) {
      s0 = bvec[tid];
      for (int k = 0; k < OUTn; k += 2) {
        s0 += ul[k] * Wu[k * OUTn + tid] + pl[k] * Wp[k * OUTn + tid];
        s1 += ul[k + 1] * Wu[(k + 1) * OUTn + tid] + pl[k + 1] * Wp[(k + 1) * OUTn + tid];
      }
    }
    biasP[(size_t)b * NPAD + tid] = s0 + s1;
  }
}

// Fused, 4x finer decomposition than v1:
// block = 256 thr = ONE 32-row segment; wave w: mh=w>>1 owns rows mh*16..+16,
// nh=w&1 owns n-tiles nh*7..+7.  16 waves/CU (vs 8), B-fragments double-
// buffered 1 iter ahead (pre-MFMA vmcnt wait only drains last iter's loads),
// branchless 4-way-split weighted sum with alphas broadcast via shfl.
__global__ __launch_bounds__(256, 4) void fused_kernel(
    const float* __restrict__ H, const unsigned short* __restrict__ WhF,
    const float* __restrict__ biasP, const float* __restrict__ vP,
    const int* __restrict__ offs, float* __restrict__ out) {
  __shared__ float scp[2][32];        // partial scores per n-half
  __shared__ float o_l[4][HIDn];      // per-wave weighted-sum partials

  int tid = threadIdx.x, wave = tid >> 6, lane = tid & 63;
  int quad = lane >> 4, l16 = lane & 15;
  int mh = wave >> 1, nh = wave & 1;
  int bid = blockIdx.x;
  int b = bid >> 4, seg = bid & 15;
  int s0 = seg << 5;

  f32x4 acc[NTW];
#pragma unroll
  for (int j = 0; j < NTW; ++j) acc[j] = (f32x4){0.f, 0.f, 0.f, 0.f};

  const float* Abase = H + (size_t)(b * Sn + s0 + mh * 16 + l16) * HIDn + quad * 8;
  const short8* Bw = (const short8*)WhF + lane;  // + (it*NT+nt)*64 per fragment

  float4 f[2][2];        // A double buffer: [buf][half]
  short8 bfr[2][NTW];    // B double buffer: [buf][tile]
  f[0][0] = *(const float4*)Abase;
  f[0][1] = *(const float4*)(Abase + 4);
#pragma unroll
  for (int j = 0; j < NTW; ++j)
    bfr[0][j] = Bw[(nh * NTW + j) * 64];

#pragma unroll
  for (int it = 0; it < KIT; ++it) {
    int cur = it & 1;
    // issue next iteration's A and B loads FIRST (oldest-outstanding loads
    // are the ones consumed below, so the wait doesn't drain these)
    if (it + 1 < KIT) {
      const float* ap = Abase + (it + 1) * 32;
      f[1 - cur][0] = *(const float4*)ap;
      f[1 - cur][1] = *(const float4*)(ap + 4);
#pragma unroll
      for (int j = 0; j < NTW; ++j)
        bfr[1 - cur][j] = Bw[((it + 1) * NT + nh * NTW + j) * 64];
    }
    short8 a;
    a[0] = f2bf(f[cur][0].x); a[1] = f2bf(f[cur][0].y);
    a[2] = f2bf(f[cur][0].z); a[3] = f2bf(f[cur][0].w);
    a[4] = f2bf(f[cur][1].x); a[5] = f2bf(f[cur][1].y);
    a[6] = f2bf(f[cur][1].z); a[7] = f2bf(f[cur][1].w);
#pragma unroll
    for (int j = 0; j < NTW; ++j)
      acc[j] = __builtin_amdgcn_mfma_f32_16x16x32_bf16(a, bfr[cur][j], acc[j], 0, 0, 0);
  }

  // ---- partial scores over this wave's 112 n-cols, reduced over l16
  {
    const float* bp = biasP + (size_t)b * NPAD + nh * (NTW * 16) + l16;
    const float* vp = vP + nh * (NTW * 16) + l16;
    float bv[NTW], vv[NTW];
#pragma unroll
    for (int j = 0; j < NTW; ++j) { bv[j] = bp[j * 16]; vv[j] = vp[j * 16]; }
#pragma unroll
    for (int r = 0; r < 4; ++r) {
      float s = 0.f;
#pragma unroll
      for (int j = 0; j < NTW; ++j)
        s += fast_tanh(acc[j][r] + bv[j]) * vv[j];
      s += __shfl_xor(s, 1); s += __shfl_xor(s, 2);
      s += __shfl_xor(s, 4); s += __shfl_xor(s, 8);
      if (l16 == 0) scp[nh][mh * 16 + quad * 4 + r] = s;
    }
  }
  __syncthreads();

  // ---- segment softmax (computed redundantly by all 4 waves; lane j <-> row j)
  int beg = offs[b * (MSEG + 1) + seg];
  int nxt = offs[b * (MSEG + 1) + seg + 1];
  bool valid = (beg != -1);
  int end = (nxt == -1) ? Sn : nxt - 1;

  float x = -INFINITY;
  if (lane < 32) {
    int row = s0 + lane;
    if (valid && row >= beg && row < end)
      x = scp[0][lane] + scp[1][lane];
  }
  float mx = x;
  mx = fmaxf(mx, __shfl_xor(mx, 1));  mx = fmaxf(mx, __shfl_xor(mx, 2));
  mx = fmaxf(mx, __shfl_xor(mx, 4));  mx = fmaxf(mx, __shfl_xor(mx, 8));
  mx = fmaxf(mx, __shfl_xor(mx, 16)); mx = fmaxf(mx, __shfl_xor(mx, 32));
  float mm = (mx > -1e30f) ? mx : 0.f;
  float e = __expf(x - mm);           // exp(-inf)=0 handles masking; lanes>=32 -> 0
  float ls = e;
  ls += __shfl_xor(ls, 1);  ls += __shfl_xor(ls, 2);
  ls += __shfl_xor(ls, 4);  ls += __shfl_xor(ls, 8);
  ls += __shfl_xor(ls, 16); ls += __shfl_xor(ls, 32);
  float inv = (ls > 0.f) ? 1.f / ls : 0.f;
  float av = e * inv;                 // alpha of row `lane` (lane<32)

  // alphas for this wave's 8 rows, into registers (no LDS in the hot loop)
  float af[8];
#pragma unroll
  for (int i = 0; i < 8; ++i) af[i] = __shfl(av, wave * 8 + i);

  // ---- weighted sum: wave handles rows s0+wave*8 .. +8, full 768 cols,
  // branchless (masked rows have alpha exactly 0)
  const float4* Hrow = (const float4*)(H + (size_t)(b * Sn + s0 + wave * 8) * HIDn);
  float4 o0 = {0,0,0,0}, o1 = {0,0,0,0}, o2 = {0,0,0,0};
#pragma unroll
  for (int i = 0; i < 8; ++i) {
    const float4* hp = Hrow + (size_t)i * (HIDn / 4);
    float4 h0 = hp[lane], h1 = hp[lane + 64], h2 = hp[lane + 128];
    float a = af[i];
    o0.x += a * h0.x; o0.y += a * h0.y; o0.z += a * h0.z; o0.w += a * h0.w;
    o1.x += a * h1.x; o1.y += a * h1.y; o1.z += a * h1.z; o1.w += a * h1.w;
    o2.x += a * h2.x; o2.y += a * h2.y; o2.z += a * h2.z; o2.w += a * h2.w;
  }
  {
    float4* ol = (float4*)o_l[wave];
    ol[lane] = o0; ol[lane + 64] = o1; ol[lane + 128] = o2;
  }
  __syncthreads();

  // ---- combine 4 partials + store (192 threads x float4 = 768 cols)
  if (tid < 192) {
    const float4* p0 = (const float4*)o_l[0];
    const float4* p1 = (const float4*)o_l[1];
    const float4* p2 = (const float4*)o_l[2];
    const float4* p3 = (const float4*)o_l[3];
    float4 a0 = p0[tid], a1 = p1[tid], a2 = p2[tid], a3 = p3[tid];
    float4 s;
    s.x = a0.x + a1.x + a2.x + a3.x;
    s.y = a0.y + a1.y + a2.y + a3.y;
    s.z = a0.z + a1.z + a2.z + a3.z;
    s.w = a0.w + a1.w + a2.w + a3.w;
    ((float4*)(out + ((size_t)b * MSEG + seg) * HIDn))[tid] = s;
  }
}

extern "C" void kernel_launch(void* const* d_in, const int* in_sizes, int n_in,
                              void* d_out, int out_size, void* d_ws, size_t ws_size,
                              hipStream_t stream) {
  const float* H    = (const float*)d_in[0];
  const float* u    = (const float*)d_in[1];
  const float* p    = (const float*)d_in[2];
  const float* Wh   = (const float*)d_in[3];
  const float* Wu   = (const float*)d_in[4];
  const float* Wp   = (const float*)d_in[5];
  const float* v    = (const float*)d_in[6];
  const float* bvec = (const float*)d_in[7];
  const int*   offs = (const int*)d_in[8];
  float* out = (float*)d_out;

  // ws layout: biasP[128*224] | vP[224] | WhF (bf16 224*768, fragment order)
  float* biasP = (float*)d_ws;
  float* vP    = biasP + (size_t)Bn * NPAD;
  unsigned short* WhF = (unsigned short*)(vP + NPAD);

  setup_kernel<<<(NPAD * HIDn + 255) / 256, 256, 0, stream>>>(Wh, v, WhF, vP);
  bias_kernel<<<Bn, 256, 0, stream>>>(u, p, Wu, Wp, bvec, biasP);
  fused_kernel<<<(Bn * Sn) / 32, 256, 0, stream>>>(H, WhF, biasP, vP, offs, out);
}

// Round 2
// 375.758 us; speedup vs baseline: 1.0741x; 1.0741x over previous
//
#include <hip/hip_runtime.h>
#include <math.h>

#define Bn   128
#define Sn   512
#define HIDn 768
#define OUTn 200
#define MSEG 16
#define NPAD 224   // OUT padded to 14 MFMA n-tiles of 16
#define NT   14
#define NTW  7     // n-tiles per wave (N split across nh=0/1)
#define KIT  24    // 768/32 k-steps
#define ROWS 64    // rows per block (2 segments)

typedef __attribute__((ext_vector_type(8))) short short8;
typedef __attribute__((ext_vector_type(4))) float f32x4;

// async global->LDS, 16B per lane; dest = wave-uniform base + lane*16
#define GL2LDS(gp, lp) __builtin_amdgcn_global_load_lds(                  \
    (const __attribute__((address_space(1))) void*)(gp),                  \
    (__attribute__((address_space(3))) void*)(lp), 16, 0, 0)

// fp32 -> bf16 round-to-nearest-even (finite inputs)
static __device__ inline unsigned short f2bf(float f) {
  union { float f; unsigned u; } v; v.f = f;
  unsigned r = v.u + 0x7FFFu + ((v.u >> 16) & 1u);
  return (unsigned short)(r >> 16);
}

// saturating fast tanh: e = exp(-2|x|) in (0,1], never overflows
static __device__ inline float fast_tanh(float x) {
  float t = fabsf(x);
  float e = __expf(-2.f * t);
  float r = (1.f - e) * __builtin_amdgcn_rcpf(1.f + e);
  return copysignf(r, x);
}

// one-time: WhF = bf16(Wh^T) in MFMA B-fragment order:
// elem (n,k) -> ((k>>5)*NT + (n>>4))*512 + ((k>>3)&3)*128 + (n&15)*8 + (k&7)
// Cols 200..223 zero-padded.  vP = v zero-padded to NPAD.
__global__ __launch_bounds__(256) void setup_kernel(
    const float* __restrict__ Wh, const float* __restrict__ v,
    unsigned short* __restrict__ WhF, float* __restrict__ vP) {
  int idx = blockIdx.x * 256 + threadIdx.x;   // grid 672 -> 172032 = NPAD*HIDn
  if (blockIdx.x == 0 && threadIdx.x < NPAD)
    vP[threadIdx.x] = (threadIdx.x < OUTn) ? v[threadIdx.x] : 0.f;
  if (idx < NPAD * HIDn) {
    int n = idx / HIDn;
    int k = idx - n * HIDn;
    float val = (n < OUTn) ? Wh[(size_t)k * OUTn + n] : 0.f;
    size_t d = ((size_t)(k >> 5) * NT + (n >> 4)) * 512
             + ((k >> 3) & 3) * 128 + (n & 15) * 8 + (k & 7);
    WhF[d] = f2bf(val);
  }
}

// biasP[b][n] = b[n] + u[b]@Wu[:,n] + p[b]@Wp[:,n], zero-padded to NPAD
__global__ __launch_bounds__(256) void bias_kernel(
    const float* __restrict__ u, const float* __restrict__ p,
    const float* __restrict__ Wu, const float* __restrict__ Wp,
    const float* __restrict__ bvec, float* __restrict__ biasP) {
  int b = blockIdx.x;
  __shared__ float ul[OUTn], pl[OUTn];
  int tid = threadIdx.x;
  if (tid < OUTn) { ul[tid] = u[b * OUTn + tid]; pl[tid] = p[b * OUTn + tid]; }
  __syncthreads();
  if (tid < NPAD) {
    float s0 = 0.f, s1 = 0.f;
    if (tid < OUTn) {
      s0 = bvec[tid];
      for (int k = 0; k < OUTn; k += 2) {
        s0 += ul[k] * Wu[k * OUTn + tid] + pl[k] * Wp[k * OUTn + tid];
        s1 += ul[k + 1] * Wu[(k + 1) * OUTn + tid] + pl[k + 1] * Wp[(k + 1) * OUTn + tid];
      }
    }
    biasP[(size_t)b * NPAD + tid] = s0 + s1;
  }
}

// Fused: block = 64 rows (2 segments), 4 waves.  A staged once per block via
// double-buffered global_load_lds (async, no VGPR cost, stays in flight across
// the compute phase); 16B-chunk XOR swizzle (applied to the GLOBAL source addr,
// since gl_lds writes linearly) makes the ds_read_b128 fragment reads
// conflict-free.  Wave (mh,nh) = 32 rows x 7 n-tiles -> 14 MFMA/K-step.
// B fragments from L2-resident WhF.  Branchless epilogue.
__global__ __launch_bounds__(256) void fused_kernel(
    const float* __restrict__ H, const unsigned short* __restrict__ WhF,
    const float* __restrict__ biasP, const float* __restrict__ vP,
    const int* __restrict__ offs, float* __restrict__ out) {
  __shared__ float As[2][ROWS * 32];   // [buf][row*32 + slot*4 + j], swizzled
  __shared__ float scp[2][ROWS];       // partial scores per n-half
  __shared__ float o_l[4][HIDn];       // per-wave weighted-sum partials

  int tid = threadIdx.x, wave = tid >> 6, lane = tid & 63;
  int quad = lane >> 4, l16 = lane & 15;
  int mh = wave >> 1, nh = wave & 1;
  int bid = blockIdx.x;
  int b = bid >> 3;              // 8 blocks per batch
  int s0 = (bid & 7) << 6;       // row start within S
  int seg0 = (bid & 7) << 1;

  // ---- staging addressing (constant over kt)
  // thread stages LDS slots t0 = wave*128+lane, t1 = t0+64; slot t holds
  // source chunk (t&7) ^ ((t>>3)&7) of row t>>3  (16B chunks)
  int rstage = wave * 16 + (lane >> 3);
  int csrc   = (lane & 7) ^ ((lane >> 3) & 7);
  const float* Hblk  = H + (size_t)(b * Sn + s0) * HIDn;
  const float* gsrc0 = Hblk + (size_t)rstage * HIDn + csrc * 4;
  const float* gsrc1 = Hblk + (size_t)(rstage + 8) * HIDn + csrc * 4;
  int ldst0 = wave * 512;        // float index of wave-uniform LDS dest base
  int ldst1 = wave * 512 + 256;

  // prologue: stage kt=0 into buf 0
  GL2LDS(gsrc0, &As[0][ldst0]);
  GL2LDS(gsrc1, &As[0][ldst1]);

  f32x4 acc[2][NTW];
#pragma unroll
  for (int mt = 0; mt < 2; ++mt)
#pragma unroll
    for (int j = 0; j < NTW; ++j) acc[mt][j] = (f32x4){0.f, 0.f, 0.f, 0.f};

  const short8* Bw = (const short8*)WhF + lane;
  int sw = (l16 & 7) << 2;       // read-side swizzle (float-index XOR)

  __syncthreads();               // staging(0) complete (vmcnt drained)

#pragma unroll
  for (int kt = 0; kt < KIT; ++kt) {
    int buf = kt & 1;
    // B fragments for this step (issued before next-staging so their wait
    // keeps the staging loads in flight)
    short8 bfr[NTW];
#pragma unroll
    for (int j = 0; j < NTW; ++j)
      bfr[j] = Bw[(kt * NT + nh * NTW + j) * 64];
    // stage next K-step (async; completes by the end-of-iter barrier)
    if (kt + 1 < KIT) {
      GL2LDS(gsrc0 + (kt + 1) * 32, &As[buf ^ 1][ldst0]);
      GL2LDS(gsrc1 + (kt + 1) * 32, &As[buf ^ 1][ldst1]);
    }
    // A fragments from LDS (swizzled, conflict-free) + convert to bf16
    short8 a[2];
#pragma unroll
    for (int mt = 0; mt < 2; ++mt) {
      const float* Ab = &As[buf][(mh * 32 + mt * 16 + l16) * 32];
      float4 h0 = *(const float4*)(Ab + ((quad * 8)     ^ sw));
      float4 h1 = *(const float4*)(Ab + ((quad * 8 + 4) ^ sw));
      short8 t;
      t[0] = f2bf(h0.x); t[1] = f2bf(h0.y); t[2] = f2bf(h0.z); t[3] = f2bf(h0.w);
      t[4] = f2bf(h1.x); t[5] = f2bf(h1.y); t[6] = f2bf(h1.z); t[7] = f2bf(h1.w);
      a[mt] = t;
    }
#pragma unroll
    for (int j = 0; j < NTW; ++j) {
      acc[0][j] = __builtin_amdgcn_mfma_f32_16x16x32_bf16(a[0], bfr[j], acc[0][j], 0, 0, 0);
      acc[1][j] = __builtin_amdgcn_mfma_f32_16x16x32_bf16(a[1], bfr[j], acc[1][j], 0, 0, 0);
    }
    __syncthreads();             // staging(kt+1) done; buf safe to overwrite
  }

  // ---- partial scores over this wave's 112 n-cols, reduced over l16
  {
    const float* bp = biasP + (size_t)b * NPAD + nh * (NTW * 16) + l16;
    const float* vp = vP + nh * (NTW * 16) + l16;
    float bv[NTW], vv[NTW];
#pragma unroll
    for (int j = 0; j < NTW; ++j) { bv[j] = bp[j * 16]; vv[j] = vp[j * 16]; }
#pragma unroll
    for (int mt = 0; mt < 2; ++mt)
#pragma unroll
      for (int r = 0; r < 4; ++r) {
        float s = 0.f;
#pragma unroll
        for (int j = 0; j < NTW; ++j)
          s += fast_tanh(acc[mt][j][r] + bv[j]) * vv[j];
        s += __shfl_xor(s, 1); s += __shfl_xor(s, 2);
        s += __shfl_xor(s, 4); s += __shfl_xor(s, 8);
        if (l16 == 0) scp[nh][mh * 32 + mt * 16 + quad * 4 + r] = s;
      }
  }
  __syncthreads();

  // ---- two segment softmaxes (redundant per wave; lane j <-> block row j,
  // lanes 0..31 = segment seg0, lanes 32..63 = seg0+1; reductions stay
  // within each 32-lane group)
  int g = lane >> 5;
  int seg = seg0 + g;
  int beg = offs[b * (MSEG + 1) + seg];
  int nxt = offs[b * (MSEG + 1) + seg + 1];
  bool valid = (beg != -1);
  int end = (nxt == -1) ? Sn : nxt - 1;
  int row = s0 + lane;
  float x = (valid && row >= beg && row < end)
              ? (scp[0][lane] + scp[1][lane]) : -INFINITY;
  float mx = x;
  mx = fmaxf(mx, __shfl_xor(mx, 1));  mx = fmaxf(mx, __shfl_xor(mx, 2));
  mx = fmaxf(mx, __shfl_xor(mx, 4));  mx = fmaxf(mx, __shfl_xor(mx, 8));
  mx = fmaxf(mx, __shfl_xor(mx, 16));
  float mm = (mx > -1e30f) ? mx : 0.f;
  float e = __expf(x - mm);            // exp(-inf)=0 handles masking
  float ls = e;
  ls += __shfl_xor(ls, 1);  ls += __shfl_xor(ls, 2);
  ls += __shfl_xor(ls, 4);  ls += __shfl_xor(ls, 8);
  ls += __shfl_xor(ls, 16);
  float av = e * ((ls > 0.f) ? 1.f / ls : 0.f);  // alpha of block row `lane`

  // ---- weighted sum: wave (sgi=w>>1, rh=w&1) sums rows sgi*32+rh*16..+16,
  // full 768 cols, branchless (masked rows have alpha exactly 0)
  int sgi = wave >> 1, rh = wave & 1;
  const float4* Hrow = (const float4*)(H + (size_t)(b * Sn + s0 + sgi * 32 + rh * 16) * HIDn);
  float4 o0 = {0,0,0,0}, o1 = {0,0,0,0}, o2 = {0,0,0,0};
#pragma unroll 4
  for (int i = 0; i < 16; ++i) {
    float a4 = __shfl(av, sgi * 32 + rh * 16 + i);
    const float4* hp = Hrow + (size_t)i * (HIDn / 4);
    float4 h0 = hp[lane], h1 = hp[lane + 64], h2 = hp[lane + 128];
    o0.x += a4 * h0.x; o0.y += a4 * h0.y; o0.z += a4 * h0.z; o0.w += a4 * h0.w;
    o1.x += a4 * h1.x; o1.y += a4 * h1.y; o1.z += a4 * h1.z; o1.w += a4 * h1.w;
    o2.x += a4 * h2.x; o2.y += a4 * h2.y; o2.z += a4 * h2.z; o2.w += a4 * h2.w;
  }
  {
    float4* ol = (float4*)o_l[wave];
    ol[lane] = o0; ol[lane + 64] = o1; ol[lane + 128] = o2;
  }
  __syncthreads();

  // ---- combine the 2 row-half partials per segment + store
  if (tid < 192) {
    const float4* p0 = (const float4*)o_l[0];
    const float4* p1 = (const float4*)o_l[1];
    const float4* p2 = (const float4*)o_l[2];
    const float4* p3 = (const float4*)o_l[3];
    float4 a0 = p0[tid], a1 = p1[tid];
    float4 b0 = p2[tid], b1 = p3[tid];
    float4 sA, sB;
    sA.x = a0.x + a1.x; sA.y = a0.y + a1.y; sA.z = a0.z + a1.z; sA.w = a0.w + a1.w;
    sB.x = b0.x + b1.x; sB.y = b0.y + b1.y; sB.z = b0.z + b1.z; sB.w = b0.w + b1.w;
    ((float4*)(out + ((size_t)b * MSEG + seg0) * HIDn))[tid] = sA;
    ((float4*)(out + ((size_t)b * MSEG + seg0 + 1) * HIDn))[tid] = sB;
  }
}

extern "C" void kernel_launch(void* const* d_in, const int* in_sizes, int n_in,
                              void* d_out, int out_size, void* d_ws, size_t ws_size,
                              hipStream_t stream) {
  const float* H    = (const float*)d_in[0];
  const float* u    = (const float*)d_in[1];
  const float* p    = (const float*)d_in[2];
  const float* Wh   = (const float*)d_in[3];
  const float* Wu   = (const float*)d_in[4];
  const float* Wp   = (const float*)d_in[5];
  const float* v    = (const float*)d_in[6];
  const float* bvec = (const float*)d_in[7];
  const int*   offs = (const int*)d_in[8];
  float* out = (float*)d_out;

  // ws layout: biasP[128*224] | vP[224] | WhF (bf16 224*768, fragment order)
  float* biasP = (float*)d_ws;
  float* vP    = biasP + (size_t)Bn * NPAD;
  unsigned short* WhF = (unsigned short*)(vP + NPAD);

  setup_kernel<<<(NPAD * HIDn + 255) / 256, 256, 0, stream>>>(Wh, v, WhF, vP);
  bias_kernel<<<Bn, 256, 0, stream>>>(u, p, Wu, Wp, bvec, biasP);
  fused_kernel<<<(Bn * Sn) / ROWS, 256, 0, stream>>>(H, WhF, biasP, vP, offs, out);
}

// Round 3
// 375.614 us; speedup vs baseline: 1.0746x; 1.0004x over previous
//
#include <hip/hip_runtime.h>
#include <math.h>

#define Bn   128
#define Sn   512
#define HIDn 768
#define OUTn 200
#define MSEG 16
#define NPAD 224   // OUT padded to 14 MFMA n-tiles of 16
#define NT   14
#define NTW  7     // n-tiles per wave (N split across nh=0/1)
#define KIT  24    // 768/32 k-steps
#define ROWS 32    // rows per block (1 segment)
#define PH   3     // staging phases
#define KPP  8     // k-steps per phase (32KB fp32 per phase-buffer)

typedef __attribute__((ext_vector_type(8))) short short8;
typedef __attribute__((ext_vector_type(4))) float f32x4;

// async global->LDS, 16B per lane; LDS operand is the wave-uniform base,
// HW adds lane*16
#define GL2LDS(gp, lp) __builtin_amdgcn_global_load_lds(                  \
    (const __attribute__((address_space(1))) void*)(gp),                  \
    (__attribute__((address_space(3))) void*)(lp), 16, 0, 0)

// fp32 -> bf16 round-to-nearest-even (finite inputs)
static __device__ inline unsigned short f2bf(float f) {
  union { float f; unsigned u; } v; v.f = f;
  unsigned r = v.u + 0x7FFFu + ((v.u >> 16) & 1u);
  return (unsigned short)(r >> 16);
}

// saturating fast tanh: e = exp(-2|x|) in (0,1], never overflows
static __device__ inline float fast_tanh(float x) {
  float t = fabsf(x);
  float e = __expf(-2.f * t);
  float r = (1.f - e) * __builtin_amdgcn_rcpf(1.f + e);
  return copysignf(r, x);
}

// one-time: WhF = bf16(Wh^T) in MFMA B-fragment order:
// elem (n,k) -> ((k>>5)*NT + (n>>4))*512 + ((k>>3)&3)*128 + (n&15)*8 + (k&7)
// Cols 200..223 zero-padded.  vP = v zero-padded to NPAD.
__global__ __launch_bounds__(256) void setup_kernel(
    const float* __restrict__ Wh, const float* __restrict__ v,
    unsigned short* __restrict__ WhF, float* __restrict__ vP) {
  int idx = blockIdx.x * 256 + threadIdx.x;   // grid 672 -> 172032 = NPAD*HIDn
  if (blockIdx.x == 0 && threadIdx.x < NPAD)
    vP[threadIdx.x] = (threadIdx.x < OUTn) ? v[threadIdx.x] : 0.f;
  if (idx < NPAD * HIDn) {
    int n = idx / HIDn;
    int k = idx - n * HIDn;
    float val = (n < OUTn) ? Wh[(size_t)k * OUTn + n] : 0.f;
    size_t d = ((size_t)(k >> 5) * NT + (n >> 4)) * 512
             + ((k >> 3) & 3) * 128 + (n & 15) * 8 + (k & 7);
    WhF[d] = f2bf(val);
  }
}

// biasP[b][n] = b[n] + u[b]@Wu[:,n] + p[b]@Wp[:,n], zero-padded to NPAD
__global__ __launch_bounds__(256) void bias_kernel(
    const float* __restrict__ u, const float* __restrict__ p,
    const float* __restrict__ Wu, const float* __restrict__ Wp,
    const float* __restrict__ bvec, float* __restrict__ biasP) {
  int b = blockIdx.x;
  __shared__ float ul[OUTn], pl[OUTn];
  int tid = threadIdx.x;
  if (tid < OUTn) { ul[tid] = u[b * OUTn + tid]; pl[tid] = p[b * OUTn + tid]; }
  __syncthreads();
  if (tid < NPAD) {
    float s0 = 0.f, s1 = 0.f;
    if (tid < OUTn) {
      s0 = bvec[tid];
      for (int k = 0; k < OUTn; k += 2) {
        s0 += ul[k] * Wu[k * OUTn + tid] + pl[k] * Wp[k * OUTn + tid];
        s1 += ul[k + 1] * Wu[(k + 1) * OUTn + tid] + pl[k + 1] * Wp[(k + 1) * OUTn + tid];
      }
    }
    biasP[(size_t)b * NPAD + tid] = s0 + s1;
  }
}

// Fused: block = 32 rows (1 segment), 4 waves (mh = rows 16, nh = 7 n-tiles).
// A-panel staged in 3 phases x 8 k-steps: 32KB per phase via 32 gl_lds instrs
// issued in one burst (mid-phase), double-buffered.  Phase length (~3k cy) >
// HBM latency, so the per-phase __syncthreads vmcnt(0) drain is nearly free
// and each CU holds ~64KB of staging in flight (vs ~2KB in the per-K-step
// barrier versions -> the 1.4 TB/s wall).  16B-chunk swizzle slot=c^(r&7)
// applied to the GLOBAL source (gl_lds writes linearly), same XOR on read.
__global__ __launch_bounds__(256) void fused_kernel(
    const float* __restrict__ H, const unsigned short* __restrict__ WhF,
    const float* __restrict__ biasP, const float* __restrict__ vP,
    const int* __restrict__ offs, float* __restrict__ out) {
  __shared__ float As[2][KPP * 1024];  // 2 x 32KB: [ks][row][slot] (swizzled)
  __shared__ float scp[2][ROWS];       // partial scores per n-half
  __shared__ float o_l[4][HIDn];       // per-wave weighted-sum partials

  int tid = threadIdx.x, wave = tid >> 6, lane = tid & 63;
  int quad = lane >> 4, l16 = lane & 15;
  int mh = wave >> 1, nh = wave & 1;
  int bid = blockIdx.x;
  int b = bid >> 4;              // 16 blocks per batch
  int seg = bid & 15;
  int s0 = seg << 5;

  const float* Hblk = H + (size_t)(b * Sn + s0) * HIDn;

  // ---- staging invariants: instr i = wave*8+t stages subtile ks=i>>2,
  // quarter qt=i&3 (rows qt*8..+8).  Lane: row-in-quarter = lane>>3,
  // chunk-slot = lane&7 holds source chunk (lane&7)^(row&7).
  int rloc = lane >> 3;
  int csrc = (lane & 7) ^ (rloc & 7);
  const float* Hst = Hblk + (size_t)rloc * HIDn + csrc * 4;

#define STAGE(ph, bf)                                                        \
  {                                                                          \
    _Pragma("unroll")                                                        \
    for (int t = 0; t < 8; ++t) {                                            \
      int i_ = wave * 8 + t;                                                 \
      int ks_ = i_ >> 2, qt_ = i_ & 3;                                       \
      GL2LDS(Hst + (size_t)(qt_ * 8) * HIDn + ((ph) * KPP + ks_) * 32,       \
             &As[bf][ks_ * 1024 + qt_ * 256]);                               \
    }                                                                        \
  }

  f32x4 acc[NTW];
#pragma unroll
  for (int j = 0; j < NTW; ++j) acc[j] = (f32x4){0.f, 0.f, 0.f, 0.f};

  const short8* Bw = (const short8*)WhF + lane;
  int row = mh * 16 + l16;                    // this lane's A row (0..31)
  int slot0 = (2 * quad) ^ (l16 & 7);         // swizzled chunk slot for h0

  // prologue: stage phase 0 into buf 0 (one full-latency wait, once)
  STAGE(0, 0);
  __syncthreads();

#pragma unroll
  for (int ph = 0; ph < PH; ++ph) {
    int bf = ph & 1;
#pragma unroll
    for (int ks = 0; ks < KPP; ++ks) {
      int kk = ph * KPP + ks;
      // B fragments for this k-step (L2-resident WhF)
      short8 bfr[NTW];
#pragma unroll
      for (int j = 0; j < NTW; ++j)
        bfr[j] = Bw[(kk * NT + nh * NTW + j) * 64];
      // burst-issue next phase's staging after the first couple of B-waits:
      // older-than staging no longer blocks B retirement, and it gets ~6
      // k-steps (~2k cy) before its data is needed
      if (ks == 2 && ph + 1 < PH) STAGE(ph + 1, bf ^ 1);
      // A fragment from LDS (swizzled) + convert
      const float* Ab = &As[bf][ks * 1024 + row * 32];
      float4 h0 = *(const float4*)(Ab + slot0 * 4);
      float4 h1 = *(const float4*)(Ab + (slot0 ^ 1) * 4);
      short8 a;
      a[0] = f2bf(h0.x); a[1] = f2bf(h0.y); a[2] = f2bf(h0.z); a[3] = f2bf(h0.w);
      a[4] = f2bf(h1.x); a[5] = f2bf(h1.y); a[6] = f2bf(h1.z); a[7] = f2bf(h1.w);
#pragma unroll
      for (int j = 0; j < NTW; ++j)
        acc[j] = __builtin_amdgcn_mfma_f32_16x16x32_bf16(a, bfr[j], acc[j], 0, 0, 0);
    }
    __syncthreads();   // staging(ph+1) retired (issued ~6 ksteps ago) + buf free
  }

  // ---- partial scores over this wave's 112 n-cols, reduced over l16
  {
    const float* bp = biasP + (size_t)b * NPAD + nh * (NTW * 16) + l16;
    const float* vp = vP + nh * (NTW * 16) + l16;
    float bv[NTW], vv[NTW];
#pragma unroll
    for (int j = 0; j < NTW; ++j) { bv[j] = bp[j * 16]; vv[j] = vp[j * 16]; }
#pragma unroll
    for (int r = 0; r < 4; ++r) {
      float s = 0.f;
#pragma unroll
      for (int j = 0; j < NTW; ++j)
        s += fast_tanh(acc[j][r] + bv[j]) * vv[j];
      s += __shfl_xor(s, 1); s += __shfl_xor(s, 2);
      s += __shfl_xor(s, 4); s += __shfl_xor(s, 8);
      if (l16 == 0) scp[nh][mh * 16 + quad * 4 + r] = s;
    }
  }
  __syncthreads();

  // ---- segment softmax (redundant per wave; lane j <-> row j, lanes>=32 idle)
  int beg = offs[b * (MSEG + 1) + seg];
  int nxt = offs[b * (MSEG + 1) + seg + 1];
  bool valid = (beg != -1);
  int end = (nxt == -1) ? Sn : nxt - 1;

  float x = -INFINITY;
  if (lane < 32) {
    int rw = s0 + lane;
    if (valid && rw >= beg && rw < end)
      x = scp[0][lane] + scp[1][lane];
  }
  float mx = x;
  mx = fmaxf(mx, __shfl_xor(mx, 1));  mx = fmaxf(mx, __shfl_xor(mx, 2));
  mx = fmaxf(mx, __shfl_xor(mx, 4));  mx = fmaxf(mx, __shfl_xor(mx, 8));
  mx = fmaxf(mx, __shfl_xor(mx, 16)); mx = fmaxf(mx, __shfl_xor(mx, 32));
  float mm = (mx > -1e30f) ? mx : 0.f;
  float e = __expf(x - mm);            // exp(-inf)=0 handles masking
  float ls = e;
  ls += __shfl_xor(ls, 1);  ls += __shfl_xor(ls, 2);
  ls += __shfl_xor(ls, 4);  ls += __shfl_xor(ls, 8);
  ls += __shfl_xor(ls, 16); ls += __shfl_xor(ls, 32);
  float inv = (ls > 0.f) ? 1.f / ls : 0.f;
  float av = e * inv;                  // alpha of row `lane` (lane<32)

  // alphas for this wave's 8 rows, into registers (no LDS in the hot loop)
  float af[8];
#pragma unroll
  for (int i = 0; i < 8; ++i) af[i] = __shfl(av, wave * 8 + i);

  // ---- weighted sum: wave handles rows s0+wave*8 .. +8, full 768 cols,
  // branchless (masked rows have alpha exactly 0); H rows are L2/L3-hot
  const float4* Hrow = (const float4*)(H + (size_t)(b * Sn + s0 + wave * 8) * HIDn);
  float4 o0 = {0,0,0,0}, o1 = {0,0,0,0}, o2 = {0,0,0,0};
#pragma unroll
  for (int i = 0; i < 8; ++i) {
    const float4* hp = Hrow + (size_t)i * (HIDn / 4);
    float4 h0 = hp[lane], h1 = hp[lane + 64], h2 = hp[lane + 128];
    float a = af[i];
    o0.x += a * h0.x; o0.y += a * h0.y; o0.z += a * h0.z; o0.w += a * h0.w;
    o1.x += a * h1.x; o1.y += a * h1.y; o1.z += a * h1.z; o1.w += a * h1.w;
    o2.x += a * h2.x; o2.y += a * h2.y; o2.z += a * h2.z; o2.w += a * h2.w;
  }
  {
    float4* ol = (float4*)o_l[wave];
    ol[lane] = o0; ol[lane + 64] = o1; ol[lane + 128] = o2;
  }
  __syncthreads();

  // ---- combine 4 partials + store (192 threads x float4 = 768 cols)
  if (tid < 192) {
    const float4* p0 = (const float4*)o_l[0];
    const float4* p1 = (const float4*)o_l[1];
    const float4* p2 = (const float4*)o_l[2];
    const float4* p3 = (const float4*)o_l[3];
    float4 a0 = p0[tid], a1 = p1[tid], a2 = p2[tid], a3 = p3[tid];
    float4 s;
    s.x = a0.x + a1.x + a2.x + a3.x;
    s.y = a0.y + a1.y + a2.y + a3.y;
    s.z = a0.z + a1.z + a2.z + a3.z;
    s.w = a0.w + a1.w + a2.w + a3.w;
    ((float4*)(out + ((size_t)b * MSEG + seg) * HIDn))[tid] = s;
  }
}

extern "C" void kernel_launch(void* const* d_in, const int* in_sizes, int n_in,
                              void* d_out, int out_size, void* d_ws, size_t ws_size,
                              hipStream_t stream) {
  const float* H    = (const float*)d_in[0];
  const float* u    = (const float*)d_in[1];
  const float* p    = (const float*)d_in[2];
  const float* Wh   = (const float*)d_in[3];
  const float* Wu   = (const float*)d_in[4];
  const float* Wp   = (const float*)d_in[5];
  const float* v    = (const float*)d_in[6];
  const float* bvec = (const float*)d_in[7];
  const int*   offs = (const int*)d_in[8];
  float* out = (float*)d_out;

  // ws layout: biasP[128*224] | vP[224] | WhF (bf16 224*768, fragment order)
  float* biasP = (float*)d_ws;
  float* vP    = biasP + (size_t)Bn * NPAD;
  unsigned short* WhF = (unsigned short*)(vP + NPAD);

  setup_kernel<<<(NPAD * HIDn + 255) / 256, 256, 0, stream>>>(Wh, v, WhF, vP);
  bias_kernel<<<Bn, 256, 0, stream>>>(u, p, Wu, Wp, bvec, biasP);
  fused_kernel<<<(Bn * Sn) / ROWS, 256, 0, stream>>>(H, WhF, biasP, vP, offs, out);
}